// Round 6
// baseline (425.288 us; speedup 1.0000x reference)
//
#include <hip/hip_runtime.h>
#include <hip/hip_bf16.h>

#define BS    8192
#define DIM   768
#define ROWS  64        // rows per block (A panel, register/LDS resident)
#define NCT   16        // col-tiles of 256 per block (covers 4096 = half)
#define NCH   6         // K chunks of 128
#define GRID  256       // 128 row-panels x 2 col-halves, one block per CU

typedef float f32x4 __attribute__((ext_vector_type(4)));
typedef int   i32x4 __attribute__((ext_vector_type(4)));
typedef int   i32x8 __attribute__((ext_vector_type(8)));

__device__ __forceinline__ void async16(const void* g, void* l) {
    __builtin_amdgcn_global_load_lds(
        (const __attribute__((address_space(1))) unsigned int*)g,
        (__attribute__((address_space(3))) unsigned int*)l,
        16, 0, 0);
}

// One wave per row: L2-norm both embeddings, emit fp8 e4m3, diag sim in fp32.
// Blocks 0..63 also zero rowsum/colsum; block 64 zeroes the done-counter.
__global__ __launch_bounds__(256) void normalize_kernel(
    const float* __restrict__ text, const float* __restrict__ ctr,
    unsigned char* __restrict__ tq, unsigned char* __restrict__ cq,
    float* __restrict__ sim, float* __restrict__ rowsum, float* __restrict__ colsum,
    unsigned int* __restrict__ cnt) {
    if (blockIdx.x < 64) {
        const int i = blockIdx.x * 256 + threadIdx.x;   // covers 16384 = 2*BS
        rowsum[i] = 0.f;
        colsum[i] = 0.f;
    }
    if (blockIdx.x == 64 && threadIdx.x == 0) *cnt = 0u;
    const int lane = threadIdx.x & 63;
    const int row  = blockIdx.x * 4 + (threadIdx.x >> 6);
    const size_t base = (size_t)row * DIM;

    float4 t[3], c[3];
    float st = 0.f, sc = 0.f, sd = 0.f;
#pragma unroll
    for (int i = 0; i < 3; ++i) {
        t[i] = *(const float4*)&text[base + lane * 4 + i * 256];
        c[i] = *(const float4*)&ctr [base + lane * 4 + i * 256];
        st += t[i].x*t[i].x + t[i].y*t[i].y + t[i].z*t[i].z + t[i].w*t[i].w;
        sc += c[i].x*c[i].x + c[i].y*c[i].y + c[i].z*c[i].z + c[i].w*c[i].w;
        sd += t[i].x*c[i].x + t[i].y*c[i].y + t[i].z*c[i].z + t[i].w*c[i].w;
    }
#pragma unroll
    for (int off = 1; off < 64; off <<= 1) {
        st += __shfl_xor(st, off);
        sc += __shfl_xor(sc, off);
        sd += __shfl_xor(sd, off);
    }
    const float invt = 1.0f / fmaxf(sqrtf(st), 1e-8f);
    const float invc = 1.0f / fmaxf(sqrtf(sc), 1e-8f);
#pragma unroll
    for (int i = 0; i < 3; ++i) {
        unsigned int wt = (unsigned int)__builtin_amdgcn_cvt_pk_fp8_f32(t[i].x * invt, t[i].y * invt, 0, false);
        wt = (unsigned int)__builtin_amdgcn_cvt_pk_fp8_f32(t[i].z * invt, t[i].w * invt, (int)wt, true);
        unsigned int wcq = (unsigned int)__builtin_amdgcn_cvt_pk_fp8_f32(c[i].x * invc, c[i].y * invc, 0, false);
        wcq = (unsigned int)__builtin_amdgcn_cvt_pk_fp8_f32(c[i].z * invc, c[i].w * invc, (int)wcq, true);
        *(unsigned int*)&tq[base + lane * 4 + i * 256] = wt;
        *(unsigned int*)&cq[base + lane * 4 + i * 256] = wcq;
    }
    if (lane == 0) sim[row] = sd * invt * invc;
}

// Barrier-free K-loop GEMM (MX-scaled fp8, 16x16x128):
//  - block = 64 rows x 4096 cols (16 col-tiles of 256), 512 thr / 8 waves (2x4)
//  - A panel (64x768) staged to LDS once; fragments hoisted to VGPRs for all K
//    (2 mt x 6 kb x 8 regs = 96 VGPR) -> ZERO LDS traffic / barriers in K-loop
//  - B fragments loaded lane-exact from global, double-buffered one chunk
//    ahead -> compiler emits fine-grained vmcnt, no vmcnt(0) drains
//  - XCD swizzle: each XCD works one 3 MB B column-half (fits 4 MB L2)
//  - last block (agent-scope counter) computes the final loss (R5-verified).
__global__ __launch_bounds__(512, 2) void gemm_lse_kernel(
    const unsigned char* __restrict__ tq, const unsigned char* __restrict__ cq,
    float* __restrict__ rowsum, float* __restrict__ colsum,
    const float* __restrict__ sim, unsigned int* __restrict__ cnt,
    float* __restrict__ out) {
    __shared__ char ldsA[ROWS * DIM];   // 48 KB

    const int tid = threadIdx.x;
    const int bid = blockIdx.x;
    // bid&7 == XCD (round-robin dispatch): XCDs 0-3 -> col half 0, 4-7 -> half 1.
    const int xcd = bid & 7, idx = bid >> 3;          // idx 0..31
    const int colHalf  = xcd >> 2;
    const int rowPanel = (xcd & 3) * 32 + idx;        // 0..127
    const int rowBase  = rowPanel * ROWS;

    const int wave = tid >> 6, lane = tid & 63;
    const int wr = wave >> 2, wc = wave & 3;          // 2x4 waves: 32 rows x 64 cols
    const int quad = lane >> 4, l16 = lane & 15;

    // ---- Prologue: stage A panel (64 x 768 fp8) into LDS, one barrier. ----
    // 3072 16B chunks; plane pl = kb*4+quad holds [row64][32B], halves swizzled
    // by pl&1 (the R3-R5 verified conflict-free scheme; plane stride 2048 B).
    const unsigned char* gA = tq + (size_t)rowBase * DIM;
#pragma unroll
    for (int i = 0; i < 6; ++i) {
        const int p  = tid + i * 512;
        const int pl = p >> 7;
        const int r  = (p >> 1) & 63;
        const int hl = (p & 1) ^ (pl & 1);
        async16(gA + r * DIM + (pl >> 2) * 128 + (pl & 3) * 32 + hl * 16,
                ldsA + p * 16);
    }
    __syncthreads();

    // Hoist A fragments for the entire K into registers.
    const int sw = quad & 1;
    i32x8 areg[2][NCH];
#pragma unroll
    for (int mt = 0; mt < 2; ++mt)
#pragma unroll
        for (int kb = 0; kb < NCH; ++kb) {
            const int off = (kb * 4 + quad) * 2048 + (wr * 32 + mt * 16 + l16) * 32;
            i32x4 lo = *(const i32x4*)(ldsA + off + sw * 16);
            i32x4 hi = *(const i32x4*)(ldsA + off + (sw ^ 1) * 16);
            areg[mt][kb] = __builtin_shufflevector(lo, hi, 0, 1, 2, 3, 4, 5, 6, 7);
        }

    // B fragment base pointers: lane-exact 32 B per (nt, chunk).
    const unsigned char* colPtr[4];
#pragma unroll
    for (int nt = 0; nt < 4; ++nt)
        colPtr[nt] = cq + (size_t)(colHalf * 4096 + wc * 64 + nt * 16 + l16) * DIM
                        + quad * 32;

    auto ldB = [&](i32x4 (&b)[4][2], int ct, int ch) {
        const size_t o = (size_t)ct * (256 * DIM) + ch * 128;
#pragma unroll
        for (int nt = 0; nt < 4; ++nt) {
            b[nt][0] = *(const i32x4*)(colPtr[nt] + o);
            b[nt][1] = *(const i32x4*)(colPtr[nt] + o + 16);
        }
    };

    f32x4 acc[2][4];
#pragma unroll
    for (int mt = 0; mt < 2; ++mt)
#pragma unroll
        for (int nt = 0; nt < 4; ++nt)
            acc[mt][nt] = (f32x4){0.f, 0.f, 0.f, 0.f};

    float rp[2][4];   // row partials, accumulated across ALL col-tiles
#pragma unroll
    for (int mt = 0; mt < 2; ++mt)
#pragma unroll
        for (int r = 0; r < 4; ++r) rp[mt][r] = 0.f;

    i32x4 bb[2][4][2];   // double-buffered B fragments
    ldB(bb[0], 0, 0);

    for (int ct = 0; ct < NCT; ++ct) {
#pragma unroll
        for (int ch = 0; ch < NCH; ++ch) {
            const int cur = ch & 1;
            if (ch < NCH - 1)      ldB(bb[cur ^ 1], ct, ch + 1);
            else if (ct < NCT - 1) ldB(bb[cur ^ 1], ct + 1, 0);
#pragma unroll
            for (int nt = 0; nt < 4; ++nt) {
                i32x8 bf = __builtin_shufflevector(bb[cur][nt][0], bb[cur][nt][1],
                                                   0, 1, 2, 3, 4, 5, 6, 7);
#pragma unroll
                for (int mt = 0; mt < 2; ++mt)
                    acc[mt][nt] = __builtin_amdgcn_mfma_scale_f32_16x16x128_f8f6f4(
                        areg[mt][ch], bf, acc[mt][nt], 0, 0, 0, 127, 0, 127);
            }
        }
        // Col-tile epilogue: exp, fold into row partials, reduce+atomic col sums.
        float cp[4] = {0.f, 0.f, 0.f, 0.f};
#pragma unroll
        for (int mt = 0; mt < 2; ++mt)
#pragma unroll
            for (int nt = 0; nt < 4; ++nt) {
#pragma unroll
                for (int r = 0; r < 4; ++r) {
                    const float e = __expf(acc[mt][nt][r]);   // S in [-1,1]
                    rp[mt][r] += e;
                    cp[nt]    += e;
                }
                acc[mt][nt] = (f32x4){0.f, 0.f, 0.f, 0.f};
            }
#pragma unroll
        for (int nt = 0; nt < 4; ++nt) {
            float v = cp[nt];
            v += __shfl_xor(v, 16);
            v += __shfl_xor(v, 32);
            if (quad == 0)
                atomicAdd(&colsum[colHalf * 4096 + ct * 256 + wc * 64 + nt * 16 + l16], v);
        }
    }

    // Row sums: reduce across the 16 col-lanes, one atomic per row.
#pragma unroll
    for (int mt = 0; mt < 2; ++mt)
#pragma unroll
        for (int r = 0; r < 4; ++r) {
            float v = rp[mt][r];
            v += __shfl_xor(v, 1);
            v += __shfl_xor(v, 2);
            v += __shfl_xor(v, 4);
            v += __shfl_xor(v, 8);
            if (l16 == 0)
                atomicAdd(&rowsum[rowBase + wr * 32 + mt * 16 + quad * 4 + r], v);
        }

    // ---- Fused finalize: last block to finish reduces the 16K sums. ----
    float* redf = (float*)ldsA;
    unsigned int* flagp = (unsigned int*)(ldsA + 128);
    __syncthreads();
    if (tid == 0) {
        unsigned int old = __hip_atomic_fetch_add(cnt, 1u, __ATOMIC_ACQ_REL,
                                                  __HIP_MEMORY_SCOPE_AGENT);
        *flagp = (old == GRID - 1) ? 1u : 0u;
    }
    __syncthreads();
    if (*flagp) {
        float a = 0.f;
        for (int j = tid; j < BS; j += 512) {
            const float rs = __hip_atomic_load(&rowsum[j], __ATOMIC_RELAXED,
                                               __HIP_MEMORY_SCOPE_AGENT);
            const float cs = __hip_atomic_load(&colsum[j], __ATOMIC_RELAXED,
                                               __HIP_MEMORY_SCOPE_AGENT);
            a += __logf(rs) + __logf(cs) - 2.f * sim[j];
        }
#pragma unroll
        for (int off = 1; off < 64; off <<= 1) a += __shfl_xor(a, off);
        if (lane == 0) redf[wave] = a;
        __syncthreads();
        if (tid == 0) {
            float s = 0.f;
#pragma unroll
            for (int w = 0; w < 8; ++w) s += redf[w];
            out[0] = s / (float)BS;
        }
    }
}

extern "C" void kernel_launch(void* const* d_in, const int* in_sizes, int n_in,
                              void* d_out, int out_size, void* d_ws, size_t ws_size,
                              hipStream_t stream) {
    const float* text = (const float*)d_in[0];
    const float* ctr  = (const float*)d_in[1];

    char* ws = (char*)d_ws;
    const size_t embBytes = (size_t)BS * DIM;   // fp8: 6,291,456 bytes each
    unsigned char* tq = (unsigned char*)ws;
    unsigned char* cq = (unsigned char*)(ws + embBytes);
    float* sim    = (float*)(ws + 2 * embBytes);
    float* rowsum = (float*)(ws + 2 * embBytes + BS * sizeof(float));
    float* colsum = (float*)(ws + 2 * embBytes + 2 * BS * sizeof(float));
    unsigned int* cnt = (unsigned int*)(ws + 2 * embBytes + 3 * BS * sizeof(float));

    normalize_kernel<<<BS / 4, 256, 0, stream>>>(text, ctr, tq, cq, sim,
                                                 rowsum, colsum, cnt);

    gemm_lse_kernel<<<GRID, 512, 0, stream>>>(tq, cq, rowsum, colsum, sim,
                                              cnt, (float*)d_out);
}